// Round 1
// baseline (104.556 us; speedup 1.0000x reference)
//
#include <hip/hip_runtime.h>

// DWT (Haar) forward: x (B=8, C=32, H=512, W=512) fp32
//   -> out (B, 4C, H/2, W/2), out channel = 4*c + {A,H,V,D}
//
// Memory-bound streaming op: 268 MB in + 268 MB out. Each thread handles
// one (bc, i, j2) = 2 output columns: one float4 load per input row (dense
// 16B/lane) and four float2 stores (dense 8B/lane) to the 4 output planes.

__global__ __launch_bounds__(256) void dwt_haar_kernel(
    const float* __restrict__ x, float* __restrict__ out) {
    constexpr int H = 512, W = 512;
    constexpr int h = H / 2, w = W / 2;   // 256, 256
    constexpr int wp = w / 2;             // 128 float2-columns per row
    constexpr int BC = 8 * 32;            // fused batch*channel
    constexpr long long total = (long long)BC * h * wp;  // 2^23 = 8,388,608

    const long long stride = (long long)gridDim.x * blockDim.x;
    for (long long idx = (long long)blockIdx.x * blockDim.x + threadIdx.x;
         idx < total; idx += stride) {
        const int j2 = (int)(idx & (wp - 1));        // 0..127 (7 bits)
        const int i  = (int)((idx >> 7) & (h - 1));  // 0..255 (8 bits)
        const int bc = (int)(idx >> 15);             // 0..255

        const size_t in_row0 = ((size_t)bc * H + 2 * i) * W + 4 * j2;
        const float4 r0 = *reinterpret_cast<const float4*>(&x[in_row0]);
        const float4 r1 = *reinterpret_cast<const float4*>(&x[in_row0 + W]);

        // column pair 0: p00=r0.x p01=r0.y p10=r1.x p11=r1.y
        // column pair 1: p00=r0.z p01=r0.w p10=r1.z p11=r1.w
        float2 cA, cHh, cV, cD;
        {
            const float s0 = r0.x + r0.y, s1 = r1.x + r1.y;
            const float d0 = r0.x - r0.y, d1 = r1.x - r1.y;
            cA.x  = (s0 + s1) * 0.5f;
            cHh.x = (s0 - s1) * 0.5f;
            cV.x  = (d0 + d1) * 0.5f;
            cD.x  = (d0 - d1) * 0.5f;
        }
        {
            const float s0 = r0.z + r0.w, s1 = r1.z + r1.w;
            const float d0 = r0.z - r0.w, d1 = r1.z - r1.w;
            cA.y  = (s0 + s1) * 0.5f;
            cHh.y = (s0 - s1) * 0.5f;
            cV.y  = (d0 + d1) * 0.5f;
            cD.y  = (d0 - d1) * 0.5f;
        }

        const size_t plane = (size_t)h * w;  // 65536
        const size_t obase = ((size_t)(4 * bc) * h + i) * w + 2 * j2;
        *reinterpret_cast<float2*>(&out[obase])             = cA;
        *reinterpret_cast<float2*>(&out[obase + plane])     = cHh;
        *reinterpret_cast<float2*>(&out[obase + 2 * plane]) = cV;
        *reinterpret_cast<float2*>(&out[obase + 3 * plane]) = cD;
    }
}

extern "C" void kernel_launch(void* const* d_in, const int* in_sizes, int n_in,
                              void* d_out, int out_size, void* d_ws, size_t ws_size,
                              hipStream_t stream) {
    const float* x = (const float*)d_in[0];
    float* out = (float*)d_out;

    // total threads needed: 8*32*256*128 = 8,388,608; cap grid at 2048 blocks
    // (Guideline 11) and grid-stride the rest (16 iters/thread).
    const int block = 256;
    const int grid = 2048;
    dwt_haar_kernel<<<grid, block, 0, stream>>>(x, out);
}

// Round 3
// 95.393 us; speedup vs baseline: 1.0961x; 1.0961x over previous
//
#include <hip/hip_runtime.h>

// DWT (Haar) forward: x (B=8, C=32, H=512, W=512) fp32
//   -> out (B, 4C, H/2, W/2), out channel = 4*c + {A,H,V,D}
//
// Memory-bound streaming: 268 MB in + 268 MB out, zero reuse.
// Each thread owns 4 output columns: 2x 16B loads per input row
// (2 rows), 4x 16B stores (one per output plane). All accesses are
// dense 16B/lane. Non-temporal hints keep the stream out of L2/L3.
// Uses clang ext_vector float4 (native vector) because
// __builtin_nontemporal_* rejects HIP_vector_type structs.

typedef float f32x4 __attribute__((ext_vector_type(4)));

__global__ __launch_bounds__(256) void dwt_haar_kernel(
    const float* __restrict__ x, float* __restrict__ out) {
    constexpr int H = 512, W = 512;
    constexpr int h = H / 2, w = W / 2;   // 256, 256
    constexpr int wq = w / 4;             // 64 float4-columns per output row
    constexpr int BC = 8 * 32;            // fused batch*channel = 256
    constexpr int total = BC * h * wq;    // 4,194,304

    const int stride = gridDim.x * blockDim.x;
    for (int idx = blockIdx.x * blockDim.x + threadIdx.x;
         idx < total; idx += stride) {
        const int j4 = idx & (wq - 1);         // 0..63  (6 bits)
        const int i  = (idx >> 6) & (h - 1);   // 0..255 (8 bits)
        const int bc = idx >> 14;              // 0..255

        const size_t in_row0 = ((size_t)bc * H + 2 * i) * W + 8 * j4;
        const f32x4 r0a = __builtin_nontemporal_load(
            reinterpret_cast<const f32x4*>(&x[in_row0]));
        const f32x4 r0b = __builtin_nontemporal_load(
            reinterpret_cast<const f32x4*>(&x[in_row0 + 4]));
        const f32x4 r1a = __builtin_nontemporal_load(
            reinterpret_cast<const f32x4*>(&x[in_row0 + W]));
        const f32x4 r1b = __builtin_nontemporal_load(
            reinterpret_cast<const f32x4*>(&x[in_row0 + W + 4]));

        f32x4 cA, cHh, cV, cD;
        // column pair 0: (r0a.x, r0a.y) over (r1a.x, r1a.y)
        {
            const float s0 = r0a.x + r0a.y, s1 = r1a.x + r1a.y;
            const float d0 = r0a.x - r0a.y, d1 = r1a.x - r1a.y;
            cA.x  = (s0 + s1) * 0.5f;
            cHh.x = (s0 - s1) * 0.5f;
            cV.x  = (d0 + d1) * 0.5f;
            cD.x  = (d0 - d1) * 0.5f;
        }
        // column pair 1: (r0a.z, r0a.w) over (r1a.z, r1a.w)
        {
            const float s0 = r0a.z + r0a.w, s1 = r1a.z + r1a.w;
            const float d0 = r0a.z - r0a.w, d1 = r1a.z - r1a.w;
            cA.y  = (s0 + s1) * 0.5f;
            cHh.y = (s0 - s1) * 0.5f;
            cV.y  = (d0 + d1) * 0.5f;
            cD.y  = (d0 - d1) * 0.5f;
        }
        // column pair 2: (r0b.x, r0b.y) over (r1b.x, r1b.y)
        {
            const float s0 = r0b.x + r0b.y, s1 = r1b.x + r1b.y;
            const float d0 = r0b.x - r0b.y, d1 = r1b.x - r1b.y;
            cA.z  = (s0 + s1) * 0.5f;
            cHh.z = (s0 - s1) * 0.5f;
            cV.z  = (d0 + d1) * 0.5f;
            cD.z  = (d0 - d1) * 0.5f;
        }
        // column pair 3: (r0b.z, r0b.w) over (r1b.z, r1b.w)
        {
            const float s0 = r0b.z + r0b.w, s1 = r1b.z + r1b.w;
            const float d0 = r0b.z - r0b.w, d1 = r1b.z - r1b.w;
            cA.w  = (s0 + s1) * 0.5f;
            cHh.w = (s0 - s1) * 0.5f;
            cV.w  = (d0 + d1) * 0.5f;
            cD.w  = (d0 - d1) * 0.5f;
        }

        const size_t plane = (size_t)h * w;  // 65536
        const size_t obase = ((size_t)(4 * bc) * h + i) * w + 4 * j4;
        __builtin_nontemporal_store(cA,
            reinterpret_cast<f32x4*>(&out[obase]));
        __builtin_nontemporal_store(cHh,
            reinterpret_cast<f32x4*>(&out[obase + plane]));
        __builtin_nontemporal_store(cV,
            reinterpret_cast<f32x4*>(&out[obase + 2 * plane]));
        __builtin_nontemporal_store(cD,
            reinterpret_cast<f32x4*>(&out[obase + 3 * plane]));
    }
}

extern "C" void kernel_launch(void* const* d_in, const int* in_sizes, int n_in,
                              void* d_out, int out_size, void* d_ws, size_t ws_size,
                              hipStream_t stream) {
    const float* x = (const float*)d_in[0];
    float* out = (float*)d_out;

    // total threads needed: 256*256*64 = 4,194,304; cap grid at 2048 blocks
    // (Guideline 11) and grid-stride the rest (8 iters/thread).
    const int block = 256;
    const int grid = 2048;
    dwt_haar_kernel<<<grid, block, 0, stream>>>(x, out);
}